// Round 3
// baseline (546.557 us; speedup 1.0000x reference)
//
#include <hip/hip_runtime.h>
#include <math.h>

#define Bn 8
#define Tn 2048
#define En 1024
#define Hn 128
#define SQRTH 11.313708498984761f

typedef __attribute__((ext_vector_type(8))) short short8;
typedef __attribute__((ext_vector_type(4))) short short4v;
typedef __attribute__((ext_vector_type(4))) float float4v;

#define MFMA16(a, b, c) __builtin_amdgcn_mfma_f32_16x16x32_bf16((a), (b), (c), 0, 0, 0)

static __device__ __forceinline__ unsigned short f2bf(float f) {
    unsigned u = __float_as_uint(f);
    u += 0x7FFFu + ((u >> 16) & 1u);   // RNE
    return (unsigned short)(u >> 16);
}
static __device__ __forceinline__ float bf2f(unsigned short h) {
    return __uint_as_float(((unsigned)h) << 16);
}

// ---------------------------------------------------------------------------
// Kernel 0: transpose W (E,H) fp32 -> Wt (H,E) split bf16 (hi/lo)
// ---------------------------------------------------------------------------
__global__ __launch_bounds__(256) void wtrans_kernel(
    const float* __restrict__ Wq, const float* __restrict__ Wk, const float* __restrict__ Wv,
    unsigned short* __restrict__ wt_hi, unsigned short* __restrict__ wt_lo)
{
    int z = blockIdx.y;                       // 0=q 1=k 2=v
    const float* W = (z == 0) ? Wq : ((z == 1) ? Wk : Wv);
    int idx = blockIdx.x * 256 + threadIdx.x; // grid.x = 512 -> 131072
    int e = idx >> 7;
    int h = idx & 127;
    float v = W[idx];
    unsigned short hi = f2bf(v);
    unsigned short lo = f2bf(v - bf2f(hi));
    size_t o = (size_t)z * (Hn * En) + (size_t)h * En + e;
    wt_hi[o] = hi;
    wt_lo[o] = lo;
}

// ---------------------------------------------------------------------------
// Kernel 0b: x fp32 -> xh/xl split bf16 (same layout). 8 elems/thread.
// ---------------------------------------------------------------------------
__global__ __launch_bounds__(256) void xconv_kernel(
    const float* __restrict__ x,
    unsigned short* __restrict__ xh, unsigned short* __restrict__ xl)
{
    size_t idx = ((size_t)blockIdx.x * 256 + threadIdx.x) * 8;  // grid 8192
    float4v f0 = *(const float4v*)(x + idx);
    float4v f1 = *(const float4v*)(x + idx + 4);
    short8 h, l;
#pragma unroll
    for (int j = 0; j < 4; j++) {
        unsigned short h0 = f2bf(f0[j]);
        h[j] = (short)h0; l[j] = (short)f2bf(f0[j] - bf2f(h0));
        unsigned short h1 = f2bf(f1[j]);
        h[j + 4] = (short)h1; l[j + 4] = (short)f2bf(f1[j] - bf2f(h1));
    }
    *(short8*)(xh + idx) = h;
    *(short8*)(xl + idx) = l;
}

// ---------------------------------------------------------------------------
// Kernel 1: projections from pre-split bf16 x. block=256 (4 waves),
// tile 64 rows x 128 cols. z=0 -> q (split), z=1 -> k (split), z=2 -> v.
// A-fragment prefetched one kk-step ahead.
// ---------------------------------------------------------------------------
__global__ __launch_bounds__(256) void proj_kernel(
    const unsigned short* __restrict__ xh, const unsigned short* __restrict__ xl,
    const unsigned short* __restrict__ wt_hi, const unsigned short* __restrict__ wt_lo,
    unsigned short* __restrict__ q_hi, unsigned short* __restrict__ q_lo,
    unsigned short* __restrict__ k_hi, unsigned short* __restrict__ k_lo,
    unsigned short* __restrict__ vT)
{
    int z = blockIdx.y;
    int tid = threadIdx.x;
    int wave = tid >> 6, lane = tid & 63;
    int c15 = lane & 15, kg = lane >> 4;
    int row_m = blockIdx.x * 64 + wave * 16 + c15;     // A-fragment row
    const unsigned short* xrh = xh + (size_t)row_m * En;
    const unsigned short* xrl = ((z < 2) ? xl : xh) + (size_t)row_m * En;
    const unsigned short* wh = wt_hi + (size_t)z * (Hn * En);
    const unsigned short* wl = wt_lo + (size_t)z * (Hn * En);

    float4v acc[8];
#pragma unroll
    for (int i = 0; i < 8; i++) acc[i] = (float4v)0.0f;

    short8 ah = *(const short8*)(xrh + kg * 8);
    short8 al = *(const short8*)(xrl + kg * 8);

    for (int kk = 0; kk < En; kk += 32) {
        int kn = (kk + 32 < En) ? kk + 32 : 0;
        short8 ahn = *(const short8*)(xrh + kn + kg * 8);
        short8 aln = *(const short8*)(xrl + kn + kg * 8);
        if (z < 2) {
#pragma unroll
            for (int nt = 0; nt < 8; nt++) {
                size_t bo = (size_t)(nt * 16 + c15) * En + kk + kg * 8;
                short8 bh = *(const short8*)(wh + bo);
                short8 bl = *(const short8*)(wl + bo);
                acc[nt] = MFMA16(ah, bh, acc[nt]);
                acc[nt] = MFMA16(ah, bl, acc[nt]);
                acc[nt] = MFMA16(al, bh, acc[nt]);
            }
        } else {
#pragma unroll
            for (int nt = 0; nt < 8; nt++) {
                size_t bo = (size_t)(nt * 16 + c15) * En + kk + kg * 8;
                short8 bh = *(const short8*)(wh + bo);
                acc[nt] = MFMA16(ah, bh, acc[nt]);
            }
        }
        ah = ahn; al = aln;
    }

    int t_base = blockIdx.x * 64 + wave * 16 + kg * 4;   // C/D rows
    if (z < 2) {
        unsigned short* oh = (z == 0) ? q_hi : k_hi;
        unsigned short* ol = (z == 0) ? q_lo : k_lo;
#pragma unroll
        for (int nt = 0; nt < 8; nt++) {
            int h = nt * 16 + c15;
#pragma unroll
            for (int r = 0; r < 4; r++) {
                float v = acc[nt][r];
                unsigned short hh = f2bf(v);
                unsigned short ll = f2bf(v - bf2f(hh));
                size_t o = (size_t)(t_base + r) * Hn + h;
                oh[o] = hh;
                ol[o] = ll;
            }
        }
    } else {
        int b = t_base >> 11;
        int t0 = t_base & 2047;
#pragma unroll
        for (int nt = 0; nt < 8; nt++) {
            int h = nt * 16 + c15;
            short4v pk;
#pragma unroll
            for (int r = 0; r < 4; r++) pk[r] = (short)f2bf(acc[nt][r]);
            *(short4v*)(vT + ((size_t)b * Hn + h) * Tn + t0) = pk;
        }
    }
}

// ---------------------------------------------------------------------------
// Kernel 1-alt: fallback projection reading fp32 x (used if ws too small
// for the pre-split x). Identical to round-2 proj.
// ---------------------------------------------------------------------------
__global__ __launch_bounds__(256) void proj_fp32_kernel(
    const float* __restrict__ x,
    const unsigned short* __restrict__ wt_hi, const unsigned short* __restrict__ wt_lo,
    unsigned short* __restrict__ q_hi, unsigned short* __restrict__ q_lo,
    unsigned short* __restrict__ k_hi, unsigned short* __restrict__ k_lo,
    unsigned short* __restrict__ vT)
{
    int z = blockIdx.y;
    int tid = threadIdx.x;
    int wave = tid >> 6, lane = tid & 63;
    int c15 = lane & 15, kg = lane >> 4;
    int row_m = blockIdx.x * 64 + wave * 16 + c15;
    const float* xrow = x + (size_t)row_m * En;
    const unsigned short* wh = wt_hi + (size_t)z * (Hn * En);
    const unsigned short* wl = wt_lo + (size_t)z * (Hn * En);

    float4v acc[8];
#pragma unroll
    for (int i = 0; i < 8; i++) acc[i] = (float4v)0.0f;

    for (int kk = 0; kk < En; kk += 32) {
        const float* ap = xrow + kk + kg * 8;
        float4v f0 = *(const float4v*)ap;
        float4v f1 = *(const float4v*)(ap + 4);
        short8 ah, al;
#pragma unroll
        for (int j = 0; j < 4; j++) {
            unsigned short h0 = f2bf(f0[j]);
            ah[j] = (short)h0; al[j] = (short)f2bf(f0[j] - bf2f(h0));
            unsigned short h1 = f2bf(f1[j]);
            ah[j + 4] = (short)h1; al[j + 4] = (short)f2bf(f1[j] - bf2f(h1));
        }
        if (z < 2) {
#pragma unroll
            for (int nt = 0; nt < 8; nt++) {
                size_t bo = (size_t)(nt * 16 + c15) * En + kk + kg * 8;
                short8 bh = *(const short8*)(wh + bo);
                short8 bl = *(const short8*)(wl + bo);
                acc[nt] = MFMA16(ah, bh, acc[nt]);
                acc[nt] = MFMA16(ah, bl, acc[nt]);
                acc[nt] = MFMA16(al, bh, acc[nt]);
            }
        } else {
#pragma unroll
            for (int nt = 0; nt < 8; nt++) {
                size_t bo = (size_t)(nt * 16 + c15) * En + kk + kg * 8;
                short8 bh = *(const short8*)(wh + bo);
                acc[nt] = MFMA16(ah, bh, acc[nt]);
            }
        }
    }

    int t_base = blockIdx.x * 64 + wave * 16 + kg * 4;
    if (z < 2) {
        unsigned short* oh = (z == 0) ? q_hi : k_hi;
        unsigned short* ol = (z == 0) ? q_lo : k_lo;
#pragma unroll
        for (int nt = 0; nt < 8; nt++) {
            int h = nt * 16 + c15;
#pragma unroll
            for (int r = 0; r < 4; r++) {
                float v = acc[nt][r];
                unsigned short hh = f2bf(v);
                unsigned short ll = f2bf(v - bf2f(hh));
                size_t o = (size_t)(t_base + r) * Hn + h;
                oh[o] = hh;
                ol[o] = ll;
            }
        }
    } else {
        int b = t_base >> 11;
        int t0 = t_base & 2047;
#pragma unroll
        for (int nt = 0; nt < 8; nt++) {
            int h = nt * 16 + c15;
            short4v pk;
#pragma unroll
            for (int r = 0; r < 4; r++) pk[r] = (short)f2bf(acc[nt][r]);
            *(short4v*)(vT + ((size_t)b * Hn + h) * Tn + t0) = pk;
        }
    }
}

// ---------------------------------------------------------------------------
// Kernel 2: column softmax stats. att^T[s,t] = sqrtH * k[s].q[t].
// Block (4 waves) per 16 s-rows; waves split the t-loop 4-way (stride 64);
// q-fragments prefetched one step ahead; intra-wave butterfly merge, then
// 4-way LDS merge. grid (128, B).
// ---------------------------------------------------------------------------
__global__ __launch_bounds__(256) void stats_kernel(
    const unsigned short* __restrict__ q_hi, const unsigned short* __restrict__ q_lo,
    const unsigned short* __restrict__ k_hi, const unsigned short* __restrict__ k_lo,
    float* __restrict__ m_st, float* __restrict__ il_st)
{
    __shared__ float lm[4][16];
    __shared__ float ll[4][16];
    int tid = threadIdx.x;
    int wave = tid >> 6, lane = tid & 63;
    int c15 = lane & 15, kg = lane >> 4;
    int b = blockIdx.y;
    int s_base = blockIdx.x * 16;

    // A fragments: k rows (persist whole kernel)
    short8 a_h[4], a_l[4];
    {
        int s = s_base + c15;
        const unsigned short* kr = k_hi + ((size_t)(b * Tn + s)) * Hn + kg * 8;
        const unsigned short* krl = k_lo + ((size_t)(b * Tn + s)) * Hn + kg * 8;
#pragma unroll
        for (int st = 0; st < 4; st++) {
            a_h[st] = *(const short8*)(kr + st * 32);
            a_l[st] = *(const short8*)(krl + st * 32);
        }
    }
    float m[4], l[4];
#pragma unroll
    for (int r = 0; r < 4; r++) { m[r] = -3.0e38f; l[r] = 0.0f; }

    int tt0 = s_base + wave * 16;
    // preload first q fragments (tt0 may exceed range; loads stay in ws)
    short8 qc_h[4], qc_l[4];
    {
        int t = ((tt0 < Tn) ? tt0 : 0) + c15;
        const unsigned short* qr = q_hi + ((size_t)(b * Tn + t)) * Hn + kg * 8;
        const unsigned short* qrl = q_lo + ((size_t)(b * Tn + t)) * Hn + kg * 8;
#pragma unroll
        for (int st = 0; st < 4; st++) {
            qc_h[st] = *(const short8*)(qr + st * 32);
            qc_l[st] = *(const short8*)(qrl + st * 32);
        }
    }

    for (int tt = tt0; tt < Tn; tt += 64) {
        int tnext = (tt + 64 < Tn) ? tt + 64 : tt;   // clamped prefetch
        short8 qn_h[4], qn_l[4];
        {
            int t = tnext + c15;
            const unsigned short* qr = q_hi + ((size_t)(b * Tn + t)) * Hn + kg * 8;
            const unsigned short* qrl = q_lo + ((size_t)(b * Tn + t)) * Hn + kg * 8;
#pragma unroll
            for (int st = 0; st < 4; st++) {
                qn_h[st] = *(const short8*)(qr + st * 32);
                qn_l[st] = *(const short8*)(qrl + st * 32);
            }
        }
        int t = tt + c15;
        float4v acc1 = (float4v)0.0f, acc2 = (float4v)0.0f, acc3 = (float4v)0.0f;
#pragma unroll
        for (int st = 0; st < 4; st++) {
            acc1 = MFMA16(a_h[st], qc_h[st], acc1);
            acc2 = MFMA16(a_h[st], qc_l[st], acc2);
            acc3 = MFMA16(a_l[st], qc_h[st], acc3);
        }
#pragma unroll
        for (int r = 0; r < 4; r++) {
            float attv = (acc1[r] + acc2[r] + acc3[r]) * SQRTH;
            int s_row = s_base + kg * 4 + r;
            bool valid = (t >= s_row);
            float cand = valid ? attv : -3.0e38f;
            float mn = fmaxf(m[r], cand);
            l[r] = l[r] * __expf(m[r] - mn) + (valid ? __expf(attv - mn) : 0.0f);
            m[r] = mn;
        }
#pragma unroll
        for (int st = 0; st < 4; st++) { qc_h[st] = qn_h[st]; qc_l[st] = qn_l[st]; }
    }
    // merge t-subsets across the 16 lanes sharing kg
#pragma unroll
    for (int mask = 1; mask < 16; mask <<= 1) {
#pragma unroll
        for (int r = 0; r < 4; r++) {
            float mo = __shfl_xor(m[r], mask);
            float lo2 = __shfl_xor(l[r], mask);
            float mn = fmaxf(m[r], mo);
            l[r] = l[r] * __expf(m[r] - mn) + lo2 * __expf(mo - mn);
            m[r] = mn;
        }
    }
    if (c15 == 0) {
#pragma unroll
        for (int r = 0; r < 4; r++) {
            lm[wave][kg * 4 + r] = m[r];
            ll[wave][kg * 4 + r] = l[r];
        }
    }
    __syncthreads();
    if (tid < 16) {
        float mf = lm[0][tid];
#pragma unroll
        for (int w = 1; w < 4; w++) mf = fmaxf(mf, lm[w][tid]);
        float lf = 0.0f;
#pragma unroll
        for (int w = 0; w < 4; w++) lf += ll[w][tid] * __expf(lm[w][tid] - mf);
        int s = s_base + tid;
        m_st[b * Tn + s] = mf;
        il_st[b * Tn + s] = 1.0f / lf;
    }
}

// ---------------------------------------------------------------------------
// Kernel 3: output. Block (4 waves) per (b, 16-row t-tile). Waves split the
// s-tile loop (stride 4); k-fragments prefetched one 16-s half ahead;
// private fp32 partials, LDS reduction, coalesced float4 store.
// grid (128, B); heavy tiles dispatched first.
// ---------------------------------------------------------------------------
__global__ __launch_bounds__(256) void out_kernel(
    const unsigned short* __restrict__ q_hi, const unsigned short* __restrict__ q_lo,
    const unsigned short* __restrict__ k_hi, const unsigned short* __restrict__ k_lo,
    const unsigned short* __restrict__ vT,
    const float* __restrict__ m_st, const float* __restrict__ il_st,
    float* __restrict__ out)
{
    __shared__ __align__(16) unsigned short pbuf[4][16][40];
    __shared__ __align__(16) float obuf[4][16][128];   // 32 KB
    int tid = threadIdx.x;
    int wave = tid >> 6, lane = tid & 63;
    int c15 = lane & 15, kg = lane >> 4;
    int b = blockIdx.y;
    int tt = (int)gridDim.x - 1 - (int)blockIdx.x;   // heavy (high t) first
    int t_base = tt * 16;

    // A fragments: q rows (persist)
    short8 qa_h[4], qa_l[4];
    {
        int t = t_base + c15;
        const unsigned short* qr = q_hi + ((size_t)(b * Tn + t)) * Hn + kg * 8;
        const unsigned short* qrl = q_lo + ((size_t)(b * Tn + t)) * Hn + kg * 8;
#pragma unroll
        for (int st = 0; st < 4; st++) {
            qa_h[st] = *(const short8*)(qr + st * 32);
            qa_l[st] = *(const short8*)(qrl + st * 32);
        }
    }
    float4v oacc[8];
#pragma unroll
    for (int i = 0; i < 8; i++) oacc[i] = (float4v)0.0f;

    int ns = (t_base + 15) / 32 + 1;

    // preload k fragments for this wave's first half-tile
    short8 kc_h[4], kc_l[4];
    {
        int s = wave * 32 + c15;   // <= 111, always in range
        const unsigned short* kr = k_hi + ((size_t)(b * Tn + s)) * Hn + kg * 8;
        const unsigned short* krl = k_lo + ((size_t)(b * Tn + s)) * Hn + kg * 8;
#pragma unroll
        for (int st = 0; st < 4; st++) {
            kc_h[st] = *(const short8*)(kr + st * 32);
            kc_l[st] = *(const short8*)(krl + st * 32);
        }
    }

    for (int ss = wave; ss < ns; ss += 4) {
        int s0 = ss * 32;
#pragma unroll
        for (int half = 0; half < 2; half++) {
            int s16 = s0 + half * 16;
            // prefetch next half (half 1 of this tile, or half 0 of tile ss+4)
            int s16n = (half == 0) ? s16 + 16 : (ss + 4) * 32;
            if (s16n >= Tn) s16n = 0;
            short8 kn_h[4], kn_l[4];
            {
                int s = s16n + c15;
                const unsigned short* kr = k_hi + ((size_t)(b * Tn + s)) * Hn + kg * 8;
                const unsigned short* krl = k_lo + ((size_t)(b * Tn + s)) * Hn + kg * 8;
#pragma unroll
                for (int st = 0; st < 4; st++) {
                    kn_h[st] = *(const short8*)(kr + st * 32);
                    kn_l[st] = *(const short8*)(krl + st * 32);
                }
            }
            float4v acc1 = (float4v)0.0f, acc2 = (float4v)0.0f, acc3 = (float4v)0.0f;
#pragma unroll
            for (int st = 0; st < 4; st++) {
                acc1 = MFMA16(qa_h[st], kc_h[st], acc1);
                acc2 = MFMA16(qa_h[st], kc_l[st], acc2);
                acc3 = MFMA16(qa_l[st], kc_h[st], acc3);
            }
            float msv = m_st[b * Tn + s16 + c15];
            float ilv = il_st[b * Tn + s16 + c15];
#pragma unroll
            for (int r = 0; r < 4; r++) {
                int t = t_base + kg * 4 + r;
                float attv = (acc1[r] + acc2[r] + acc3[r]) * SQRTH;
                float p = (t >= s16 + c15) ? __expf(attv - msv) * ilv : 0.0f;
                pbuf[wave][kg * 4 + r][c15 + half * 16] = f2bf(p);
            }
#pragma unroll
            for (int st = 0; st < 4; st++) { kc_h[st] = kn_h[st]; kc_l[st] = kn_l[st]; }
        }
        // C-layout -> A-layout via LDS (wave-internal, DS pipe is in-order)
        short8 pa = *(const short8*)&pbuf[wave][c15][kg * 8];
#pragma unroll
        for (int nt = 0; nt < 8; nt++) {
            int h = nt * 16 + c15;
            short8 vb = *(const short8*)(vT + ((size_t)(b * Hn + h)) * Tn + s0 + kg * 8);
            oacc[nt] = MFMA16(pa, vb, oacc[nt]);
        }
    }
    // dump wave partials: oacc[nt][r] is (t_local = kg*4+r, h = nt*16+c15)
#pragma unroll
    for (int nt = 0; nt < 8; nt++) {
#pragma unroll
        for (int r = 0; r < 4; r++) {
            obuf[wave][kg * 4 + r][nt * 16 + c15] = oacc[nt][r];
        }
    }
    __syncthreads();
    // block reduction + coalesced store: 2048 floats, 8 per thread
    int e0 = tid * 8;
    int tl = e0 >> 7, h0 = e0 & 127;
    float4v r0 = (float4v)0.0f, r1 = (float4v)0.0f;
#pragma unroll
    for (int w = 0; w < 4; w++) {
        r0 += *(const float4v*)&obuf[w][tl][h0];
        r1 += *(const float4v*)&obuf[w][tl][h0 + 4];
    }
    size_t oo = ((size_t)b * Tn + t_base + tl) * Hn + h0;
    *(float4v*)(out + oo) = r0;
    *(float4v*)(out + oo + 4) = r1;
}

// ---------------------------------------------------------------------------
extern "C" void kernel_launch(void* const* d_in, const int* in_sizes, int n_in,
                              void* d_out, int out_size, void* d_ws, size_t ws_size,
                              hipStream_t stream)
{
    (void)in_sizes; (void)n_in; (void)out_size;
    const float* x  = (const float*)d_in[0];
    const float* Wk = (const float*)d_in[1];
    const float* Wq = (const float*)d_in[2];
    const float* Wv = (const float*)d_in[3];
    float* out = (float*)d_out;

    const size_t NQ = (size_t)Bn * Tn * Hn;        // 2,097,152
    const size_t NX = (size_t)Bn * Tn * En;        // 16,777,216
    unsigned short* q_hi = (unsigned short*)d_ws;
    unsigned short* q_lo = q_hi + NQ;
    unsigned short* k_hi = q_lo + NQ;
    unsigned short* k_lo = k_hi + NQ;
    unsigned short* vT   = k_lo + NQ;
    unsigned short* xh   = vT + NQ;
    unsigned short* xl   = xh + NX;
    unsigned short* wt_hi = xl + NX;
    unsigned short* wt_lo = wt_hi + (size_t)3 * Hn * En;
    float* m_st  = (float*)(wt_lo + (size_t)3 * Hn * En);
    float* il_st = m_st + (size_t)Bn * Tn;
    size_t need = (size_t)(il_st + (size_t)Bn * Tn) - (size_t)d_ws;

    wtrans_kernel<<<dim3(512, 3), 256, 0, stream>>>(Wq, Wk, Wv, wt_hi, wt_lo);
    if (ws_size >= need) {
        xconv_kernel<<<dim3(8192), 256, 0, stream>>>(x, xh, xl);
        proj_kernel<<<dim3(256, 3), 256, 0, stream>>>(xh, xl, wt_hi, wt_lo,
                                                      q_hi, q_lo, k_hi, k_lo, vT);
    } else {
        // compact layout fallback: wt arrays directly after vT
        unsigned short* wt_hi2 = vT + NQ;
        unsigned short* wt_lo2 = wt_hi2 + (size_t)3 * Hn * En;
        float* m2  = (float*)(wt_lo2 + (size_t)3 * Hn * En);
        float* il2 = m2 + (size_t)Bn * Tn;
        wtrans_kernel<<<dim3(512, 3), 256, 0, stream>>>(Wq, Wk, Wv, wt_hi2, wt_lo2);
        proj_fp32_kernel<<<dim3(256, 3), 256, 0, stream>>>(x, wt_hi2, wt_lo2,
                                                           q_hi, q_lo, k_hi, k_lo, vT);
        stats_kernel<<<dim3(128, Bn), 256, 0, stream>>>(q_hi, q_lo, k_hi, k_lo, m2, il2);
        out_kernel<<<dim3(128, Bn), 256, 0, stream>>>(q_hi, q_lo, k_hi, k_lo, vT, m2, il2, out);
        return;
    }
    stats_kernel<<<dim3(128, Bn), 256, 0, stream>>>(q_hi, q_lo, k_hi, k_lo, m_st, il_st);
    out_kernel<<<dim3(128, Bn), 256, 0, stream>>>(q_hi, q_lo, k_hi, k_lo, vT, m_st, il_st, out);
}

// Round 4
// 411.113 us; speedup vs baseline: 1.3295x; 1.3295x over previous
//
#include <hip/hip_runtime.h>
#include <math.h>

#define Bn 8
#define Tn 2048
#define En 1024
#define Hn 128
#define SQRTH 11.313708498984761f

typedef __attribute__((ext_vector_type(8))) short short8;
typedef __attribute__((ext_vector_type(4))) short short4v;
typedef __attribute__((ext_vector_type(4))) float float4v;

#define MFMA16(a, b, c) __builtin_amdgcn_mfma_f32_16x16x32_bf16((a), (b), (c), 0, 0, 0)

static __device__ __forceinline__ unsigned short f2bf(float f) {
    unsigned u = __float_as_uint(f);
    u += 0x7FFFu + ((u >> 16) & 1u);   // RNE
    return (unsigned short)(u >> 16);
}
static __device__ __forceinline__ float bf2f(unsigned short h) {
    return __uint_as_float(((unsigned)h) << 16);
}

// async global->LDS, 16 B per lane. LDS dest is wave-uniform base + lane*16.
static __device__ __forceinline__ void gll16(const unsigned short* g, unsigned short* l) {
    __builtin_amdgcn_global_load_lds(
        (const __attribute__((address_space(1))) unsigned int*)g,
        (__attribute__((address_space(3))) unsigned int*)l, 16, 0, 0);
}

// ---------------------------------------------------------------------------
// Kernel 0: W (E,H) fp32 -> K-tiled split bf16 wtt[z][ks][128 h][32 k]
// dst-linear mapping, 8 elems (along k) per thread. 192 blocks x 256.
// ---------------------------------------------------------------------------
__global__ __launch_bounds__(256) void wtrans_kernel(
    const float* __restrict__ Wq, const float* __restrict__ Wk, const float* __restrict__ Wv,
    unsigned short* __restrict__ wtt_hi, unsigned short* __restrict__ wtt_lo)
{
    int t = blockIdx.x * 256 + threadIdx.x;   // 0..49151
    int kc8 = t & 3;
    int hh = (t >> 2) & 127;
    int ks = (t >> 9) & 31;
    int z = t >> 14;
    const float* W = (z == 0) ? Wq : ((z == 1) ? Wk : Wv);
    short8 h8, l8;
#pragma unroll
    for (int j = 0; j < 8; j++) {
        int e = ks * 32 + kc8 * 8 + j;
        float v = W[(size_t)e * Hn + hh];
        unsigned short hi = f2bf(v);
        h8[j] = (short)hi;
        l8[j] = (short)f2bf(v - bf2f(hi));
    }
    size_t d = (((size_t)z * 32 + ks) * 4096) + (size_t)hh * 32 + kc8 * 8;
    *(short8*)(wtt_hi + d) = h8;
    *(short8*)(wtt_lo + d) = l8;
}

// ---------------------------------------------------------------------------
// Kernel 0b: x fp32 -> K-tiled split bf16 xt[mt][ks][64 r][32 k].
// dst-linear, 8 elems/thread. 8192 blocks x 256.
// ---------------------------------------------------------------------------
__global__ __launch_bounds__(256) void xconv_kernel(
    const float* __restrict__ x,
    unsigned short* __restrict__ xt_hi, unsigned short* __restrict__ xt_lo)
{
    int g = blockIdx.x * 256 + threadIdx.x;   // 0..2097151
    int kc8 = g & 3;
    int rr = (g >> 2) & 63;
    int ks = (g >> 8) & 31;
    int mt = g >> 13;
    size_t src = ((size_t)mt * 64 + rr) * En + ks * 32 + kc8 * 8;
    float4v f0 = *(const float4v*)(x + src);
    float4v f1 = *(const float4v*)(x + src + 4);
    short8 h, l;
#pragma unroll
    for (int j = 0; j < 4; j++) {
        unsigned short h0 = f2bf(f0[j]);
        h[j] = (short)h0; l[j] = (short)f2bf(f0[j] - bf2f(h0));
        unsigned short h1 = f2bf(f1[j]);
        h[j + 4] = (short)h1; l[j + 4] = (short)f2bf(f1[j] - bf2f(h1));
    }
    size_t d = (size_t)g * 8;
    *(short8*)(xt_hi + d) = h;
    *(short8*)(xt_lo + d) = l;
}

// ---------------------------------------------------------------------------
// Kernel 1: projections, m97-style LDS double-buffered GEMM.
// Block 256 thr = 4 waves (2x2: M32 x N64 each), tile M64 x N128, BK=32.
// LDS buffer 24 KB: A_hi[64x32] | A_lo | B_hi[128x32] | B_lo. Dbuf = 48 KB
// -> 3 blocks/CU. Staging via global_load_lds from K-tiled layouts.
// z=0 -> q (split hi/lo), z=1 -> k (split), z=2 -> v (hi only, (B,H,T)).
// ---------------------------------------------------------------------------
__global__ __launch_bounds__(256) void proj_kernel(
    const unsigned short* __restrict__ xt_hi, const unsigned short* __restrict__ xt_lo,
    const unsigned short* __restrict__ wtt_hi, const unsigned short* __restrict__ wtt_lo,
    unsigned short* __restrict__ q_hi, unsigned short* __restrict__ q_lo,
    unsigned short* __restrict__ k_hi, unsigned short* __restrict__ k_lo,
    unsigned short* __restrict__ vT)
{
    __shared__ __align__(16) unsigned short lds[2][12288];  // 48 KB
    int z = blockIdx.y;
    int mt = blockIdx.x;                       // 0..255
    int tid = threadIdx.x;
    int wave = tid >> 6, lane = tid & 63;
    int c15 = lane & 15, kg = lane >> 4;
    int mrow = wave >> 1, ncol = wave & 1;     // 2x2 wave grid

    const unsigned short* Ah0 = xt_hi + (size_t)mt * 32 * 2048;
    const unsigned short* Al0 = xt_lo + (size_t)mt * 32 * 2048;
    const unsigned short* Bh0 = wtt_hi + (size_t)z * 32 * 4096;
    const unsigned short* Bl0 = wtt_lo + (size_t)z * 32 * 4096;

    float4v acc[2][4];
#pragma unroll
    for (int i = 0; i < 2; i++)
#pragma unroll
        for (int j = 0; j < 4; j++) acc[i][j] = (float4v)0.0f;

    // ---- staging helper (wave-split chunk issue) ----
    auto stage = [&](int buf, int ks) {
        unsigned short* Lb = lds[buf];
        const unsigned short* Ah = Ah0 + ks * 2048;
        const unsigned short* Al = Al0 + ks * 2048;
        const unsigned short* Bh = Bh0 + ks * 4096;
        const unsigned short* Bl = Bl0 + ks * 4096;
        int lo8 = lane * 8;
        if (z < 2) {
#pragma unroll
            for (int i = 0; i < 6; i++) {
                int ch = wave * 6 + i;
                const unsigned short* g;
                unsigned short* l;
                if (ch < 4)       { g = Ah + ch * 512;        l = Lb + ch * 512; }
                else if (ch < 8)  { g = Al + (ch - 4) * 512;  l = Lb + 2048 + (ch - 4) * 512; }
                else if (ch < 16) { g = Bh + (ch - 8) * 512;  l = Lb + 4096 + (ch - 8) * 512; }
                else              { g = Bl + (ch - 16) * 512; l = Lb + 8192 + (ch - 16) * 512; }
                gll16(g + lo8, l + lo8);
            }
        } else {
#pragma unroll
            for (int i = 0; i < 3; i++) {
                int ch = wave * 3 + i;   // 0..11
                const unsigned short* g;
                unsigned short* l;
                if (ch < 4) { g = Ah + ch * 512;       l = Lb + ch * 512; }
                else        { g = Bh + (ch - 4) * 512; l = Lb + 4096 + (ch - 4) * 512; }
                gll16(g + lo8, l + lo8);
            }
        }
    };

    stage(0, 0);

    for (int ks = 0; ks < 32; ks++) {
        __syncthreads();                 // drains vmcnt: buf[ks&1] staged & visible
        if (ks + 1 < 32) stage((ks + 1) & 1, ks + 1);
        const unsigned short* Lb = lds[ks & 1];

        short8 ah[2], al[2], bh[4], bl[4];
#pragma unroll
        for (int mi = 0; mi < 2; mi++) {
            int row = mrow * 32 + mi * 16 + c15;
            ah[mi] = *(const short8*)(Lb + row * 32 + kg * 8);
        }
#pragma unroll
        for (int ni = 0; ni < 4; ni++) {
            int row = ncol * 64 + ni * 16 + c15;
            bh[ni] = *(const short8*)(Lb + 4096 + row * 32 + kg * 8);
        }
        if (z < 2) {
#pragma unroll
            for (int mi = 0; mi < 2; mi++) {
                int row = mrow * 32 + mi * 16 + c15;
                al[mi] = *(const short8*)(Lb + 2048 + row * 32 + kg * 8);
            }
#pragma unroll
            for (int ni = 0; ni < 4; ni++) {
                int row = ncol * 64 + ni * 16 + c15;
                bl[ni] = *(const short8*)(Lb + 8192 + row * 32 + kg * 8);
            }
#pragma unroll
            for (int mi = 0; mi < 2; mi++)
#pragma unroll
                for (int ni = 0; ni < 4; ni++) {
                    acc[mi][ni] = MFMA16(ah[mi], bh[ni], acc[mi][ni]);
                    acc[mi][ni] = MFMA16(ah[mi], bl[ni], acc[mi][ni]);
                    acc[mi][ni] = MFMA16(al[mi], bh[ni], acc[mi][ni]);
                }
        } else {
#pragma unroll
            for (int mi = 0; mi < 2; mi++)
#pragma unroll
                for (int ni = 0; ni < 4; ni++)
                    acc[mi][ni] = MFMA16(ah[mi], bh[ni], acc[mi][ni]);
        }
    }

    // ---- epilogue ----
    if (z < 2) {
        unsigned short* oh = (z == 0) ? q_hi : k_hi;
        unsigned short* ol = (z == 0) ? q_lo : k_lo;
#pragma unroll
        for (int mi = 0; mi < 2; mi++) {
#pragma unroll
            for (int ni = 0; ni < 4; ni++) {
                int h = ncol * 64 + ni * 16 + c15;
#pragma unroll
                for (int r = 0; r < 4; r++) {
                    int t = mt * 64 + mrow * 32 + mi * 16 + kg * 4 + r;
                    float v = acc[mi][ni][r];
                    unsigned short hh = f2bf(v);
                    unsigned short ll = f2bf(v - bf2f(hh));
                    size_t o = (size_t)t * Hn + h;
                    oh[o] = hh;
                    ol[o] = ll;
                }
            }
        }
    } else {
        int b = mt >> 5;
#pragma unroll
        for (int mi = 0; mi < 2; mi++) {
            int t0 = (mt & 31) * 64 + mrow * 32 + mi * 16 + kg * 4;
#pragma unroll
            for (int ni = 0; ni < 4; ni++) {
                int h = ncol * 64 + ni * 16 + c15;
                short4v pk;
#pragma unroll
                for (int r = 0; r < 4; r++) pk[r] = (short)f2bf(acc[mi][ni][r]);
                *(short4v*)(vT + ((size_t)b * Hn + h) * Tn + t0) = pk;
            }
        }
    }
}

// ---------------------------------------------------------------------------
// Kernel 2: column softmax stats. att^T[s,t] = sqrtH * k[s].q[t].
// Block (4 waves) per 16 s-rows; waves split the t-loop 4-way (stride 64);
// q-fragments prefetched one step ahead; intra-wave butterfly merge, then
// 4-way LDS merge. grid (128, B).
// ---------------------------------------------------------------------------
__global__ __launch_bounds__(256) void stats_kernel(
    const unsigned short* __restrict__ q_hi, const unsigned short* __restrict__ q_lo,
    const unsigned short* __restrict__ k_hi, const unsigned short* __restrict__ k_lo,
    float* __restrict__ m_st, float* __restrict__ il_st)
{
    __shared__ float lm[4][16];
    __shared__ float ll[4][16];
    int tid = threadIdx.x;
    int wave = tid >> 6, lane = tid & 63;
    int c15 = lane & 15, kg = lane >> 4;
    int b = blockIdx.y;
    int s_base = blockIdx.x * 16;

    short8 a_h[4], a_l[4];
    {
        int s = s_base + c15;
        const unsigned short* kr = k_hi + ((size_t)(b * Tn + s)) * Hn + kg * 8;
        const unsigned short* krl = k_lo + ((size_t)(b * Tn + s)) * Hn + kg * 8;
#pragma unroll
        for (int st = 0; st < 4; st++) {
            a_h[st] = *(const short8*)(kr + st * 32);
            a_l[st] = *(const short8*)(krl + st * 32);
        }
    }
    float m[4], l[4];
#pragma unroll
    for (int r = 0; r < 4; r++) { m[r] = -3.0e38f; l[r] = 0.0f; }

    int tt0 = s_base + wave * 16;
    short8 qc_h[4], qc_l[4];
    {
        int t = ((tt0 < Tn) ? tt0 : 0) + c15;
        const unsigned short* qr = q_hi + ((size_t)(b * Tn + t)) * Hn + kg * 8;
        const unsigned short* qrl = q_lo + ((size_t)(b * Tn + t)) * Hn + kg * 8;
#pragma unroll
        for (int st = 0; st < 4; st++) {
            qc_h[st] = *(const short8*)(qr + st * 32);
            qc_l[st] = *(const short8*)(qrl + st * 32);
        }
    }

    for (int tt = tt0; tt < Tn; tt += 64) {
        int tnext = (tt + 64 < Tn) ? tt + 64 : tt;
        short8 qn_h[4], qn_l[4];
        {
            int t = tnext + c15;
            const unsigned short* qr = q_hi + ((size_t)(b * Tn + t)) * Hn + kg * 8;
            const unsigned short* qrl = q_lo + ((size_t)(b * Tn + t)) * Hn + kg * 8;
#pragma unroll
            for (int st = 0; st < 4; st++) {
                qn_h[st] = *(const short8*)(qr + st * 32);
                qn_l[st] = *(const short8*)(qrl + st * 32);
            }
        }
        int t = tt + c15;
        float4v acc1 = (float4v)0.0f, acc2 = (float4v)0.0f, acc3 = (float4v)0.0f;
#pragma unroll
        for (int st = 0; st < 4; st++) {
            acc1 = MFMA16(a_h[st], qc_h[st], acc1);
            acc2 = MFMA16(a_h[st], qc_l[st], acc2);
            acc3 = MFMA16(a_l[st], qc_h[st], acc3);
        }
#pragma unroll
        for (int r = 0; r < 4; r++) {
            float attv = (acc1[r] + acc2[r] + acc3[r]) * SQRTH;
            int s_row = s_base + kg * 4 + r;
            bool valid = (t >= s_row);
            float cand = valid ? attv : -3.0e38f;
            float mn = fmaxf(m[r], cand);
            l[r] = l[r] * __expf(m[r] - mn) + (valid ? __expf(attv - mn) : 0.0f);
            m[r] = mn;
        }
#pragma unroll
        for (int st = 0; st < 4; st++) { qc_h[st] = qn_h[st]; qc_l[st] = qn_l[st]; }
    }
#pragma unroll
    for (int mask = 1; mask < 16; mask <<= 1) {
#pragma unroll
        for (int r = 0; r < 4; r++) {
            float mo = __shfl_xor(m[r], mask);
            float lo2 = __shfl_xor(l[r], mask);
            float mn = fmaxf(m[r], mo);
            l[r] = l[r] * __expf(m[r] - mn) + lo2 * __expf(mo - mn);
            m[r] = mn;
        }
    }
    if (c15 == 0) {
#pragma unroll
        for (int r = 0; r < 4; r++) {
            lm[wave][kg * 4 + r] = m[r];
            ll[wave][kg * 4 + r] = l[r];
        }
    }
    __syncthreads();
    if (tid < 16) {
        float mf = lm[0][tid];
#pragma unroll
        for (int w = 1; w < 4; w++) mf = fmaxf(mf, lm[w][tid]);
        float lf = 0.0f;
#pragma unroll
        for (int w = 0; w < 4; w++) lf += ll[w][tid] * __expf(lm[w][tid] - mf);
        int s = s_base + tid;
        m_st[b * Tn + s] = mf;
        il_st[b * Tn + s] = 1.0f / lf;
    }
}

// ---------------------------------------------------------------------------
// Kernel 3: output. Block (4 waves) per (b, 16-row t-tile). Waves split the
// s-tile loop (stride 4); k-fragments prefetched one 16-s half ahead;
// private fp32 partials, LDS reduction, coalesced float4 store.
// grid (128, B); heavy tiles dispatched first.
// ---------------------------------------------------------------------------
__global__ __launch_bounds__(256) void out_kernel(
    const unsigned short* __restrict__ q_hi, const unsigned short* __restrict__ q_lo,
    const unsigned short* __restrict__ k_hi, const unsigned short* __restrict__ k_lo,
    const unsigned short* __restrict__ vT,
    const float* __restrict__ m_st, const float* __restrict__ il_st,
    float* __restrict__ out)
{
    __shared__ __align__(16) unsigned short pbuf[4][16][40];
    __shared__ __align__(16) float obuf[4][16][128];   // 32 KB
    int tid = threadIdx.x;
    int wave = tid >> 6, lane = tid & 63;
    int c15 = lane & 15, kg = lane >> 4;
    int b = blockIdx.y;
    int tt = (int)gridDim.x - 1 - (int)blockIdx.x;   // heavy (high t) first
    int t_base = tt * 16;

    short8 qa_h[4], qa_l[4];
    {
        int t = t_base + c15;
        const unsigned short* qr = q_hi + ((size_t)(b * Tn + t)) * Hn + kg * 8;
        const unsigned short* qrl = q_lo + ((size_t)(b * Tn + t)) * Hn + kg * 8;
#pragma unroll
        for (int st = 0; st < 4; st++) {
            qa_h[st] = *(const short8*)(qr + st * 32);
            qa_l[st] = *(const short8*)(qrl + st * 32);
        }
    }
    float4v oacc[8];
#pragma unroll
    for (int i = 0; i < 8; i++) oacc[i] = (float4v)0.0f;

    int ns = (t_base + 15) / 32 + 1;

    short8 kc_h[4], kc_l[4];
    {
        int s = wave * 32 + c15;
        const unsigned short* kr = k_hi + ((size_t)(b * Tn + s)) * Hn + kg * 8;
        const unsigned short* krl = k_lo + ((size_t)(b * Tn + s)) * Hn + kg * 8;
#pragma unroll
        for (int st = 0; st < 4; st++) {
            kc_h[st] = *(const short8*)(kr + st * 32);
            kc_l[st] = *(const short8*)(krl + st * 32);
        }
    }

    for (int ss = wave; ss < ns; ss += 4) {
        int s0 = ss * 32;
#pragma unroll
        for (int half = 0; half < 2; half++) {
            int s16 = s0 + half * 16;
            int s16n = (half == 0) ? s16 + 16 : (ss + 4) * 32;
            if (s16n >= Tn) s16n = 0;
            short8 kn_h[4], kn_l[4];
            {
                int s = s16n + c15;
                const unsigned short* kr = k_hi + ((size_t)(b * Tn + s)) * Hn + kg * 8;
                const unsigned short* krl = k_lo + ((size_t)(b * Tn + s)) * Hn + kg * 8;
#pragma unroll
                for (int st = 0; st < 4; st++) {
                    kn_h[st] = *(const short8*)(kr + st * 32);
                    kn_l[st] = *(const short8*)(krl + st * 32);
                }
            }
            float4v acc1 = (float4v)0.0f, acc2 = (float4v)0.0f, acc3 = (float4v)0.0f;
#pragma unroll
            for (int st = 0; st < 4; st++) {
                acc1 = MFMA16(qa_h[st], kc_h[st], acc1);
                acc2 = MFMA16(qa_h[st], kc_l[st], acc2);
                acc3 = MFMA16(qa_l[st], kc_h[st], acc3);
            }
            float msv = m_st[b * Tn + s16 + c15];
            float ilv = il_st[b * Tn + s16 + c15];
#pragma unroll
            for (int r = 0; r < 4; r++) {
                int t = t_base + kg * 4 + r;
                float attv = (acc1[r] + acc2[r] + acc3[r]) * SQRTH;
                float p = (t >= s16 + c15) ? __expf(attv - msv) * ilv : 0.0f;
                pbuf[wave][kg * 4 + r][c15 + half * 16] = f2bf(p);
            }
#pragma unroll
            for (int st = 0; st < 4; st++) { kc_h[st] = kn_h[st]; kc_l[st] = kn_l[st]; }
        }
        short8 pa = *(const short8*)&pbuf[wave][c15][kg * 8];
#pragma unroll
        for (int nt = 0; nt < 8; nt++) {
            int h = nt * 16 + c15;
            short8 vb = *(const short8*)(vT + ((size_t)(b * Hn + h)) * Tn + s0 + kg * 8);
            oacc[nt] = MFMA16(pa, vb, oacc[nt]);
        }
    }
#pragma unroll
    for (int nt = 0; nt < 8; nt++) {
#pragma unroll
        for (int r = 0; r < 4; r++) {
            obuf[wave][kg * 4 + r][nt * 16 + c15] = oacc[nt][r];
        }
    }
    __syncthreads();
    int e0 = tid * 8;
    int tl = e0 >> 7, h0 = e0 & 127;
    float4v r0 = (float4v)0.0f, r1 = (float4v)0.0f;
#pragma unroll
    for (int w = 0; w < 4; w++) {
        r0 += *(const float4v*)&obuf[w][tl][h0];
        r1 += *(const float4v*)&obuf[w][tl][h0 + 4];
    }
    size_t oo = ((size_t)b * Tn + t_base + tl) * Hn + h0;
    *(float4v*)(out + oo) = r0;
    *(float4v*)(out + oo + 4) = r1;
}

// ---------------------------------------------------------------------------
extern "C" void kernel_launch(void* const* d_in, const int* in_sizes, int n_in,
                              void* d_out, int out_size, void* d_ws, size_t ws_size,
                              hipStream_t stream)
{
    (void)in_sizes; (void)n_in; (void)out_size; (void)ws_size;
    const float* x  = (const float*)d_in[0];
    const float* Wk = (const float*)d_in[1];
    const float* Wq = (const float*)d_in[2];
    const float* Wv = (const float*)d_in[3];
    float* out = (float*)d_out;

    const size_t NQ = (size_t)Bn * Tn * Hn;        // 2,097,152
    const size_t NX = (size_t)Bn * Tn * En;        // 16,777,216
    unsigned short* q_hi = (unsigned short*)d_ws;
    unsigned short* q_lo = q_hi + NQ;
    unsigned short* k_hi = q_lo + NQ;
    unsigned short* k_lo = k_hi + NQ;
    unsigned short* vT   = k_lo + NQ;
    unsigned short* xt_hi = vT + NQ;
    unsigned short* xt_lo = xt_hi + NX;
    unsigned short* wtt_hi = xt_lo + NX;
    unsigned short* wtt_lo = wtt_hi + (size_t)3 * Hn * En;
    float* m_st  = (float*)(wtt_lo + (size_t)3 * Hn * En);
    float* il_st = m_st + (size_t)Bn * Tn;
    // total ws use: ~89 MB

    wtrans_kernel<<<dim3(192), 256, 0, stream>>>(Wq, Wk, Wv, wtt_hi, wtt_lo);
    xconv_kernel<<<dim3(8192), 256, 0, stream>>>(x, xt_hi, xt_lo);
    proj_kernel<<<dim3(256, 3), 256, 0, stream>>>(xt_hi, xt_lo, wtt_hi, wtt_lo,
                                                  q_hi, q_lo, k_hi, k_lo, vT);
    stats_kernel<<<dim3(128, Bn), 256, 0, stream>>>(q_hi, q_lo, k_hi, k_lo, m_st, il_st);
    out_kernel<<<dim3(128, Bn), 256, 0, stream>>>(q_hi, q_lo, k_hi, k_lo, vT, m_st, il_st, out);
}

// Round 7
// 364.049 us; speedup vs baseline: 1.5013x; 1.1293x over previous
//
#include <hip/hip_runtime.h>
#include <math.h>

#define Bn 8
#define Tn 2048
#define En 1024
#define Hn 128
#define SQRTH 11.313708498984761f

typedef __attribute__((ext_vector_type(8))) short short8;
typedef __attribute__((ext_vector_type(4))) short short4v;
typedef __attribute__((ext_vector_type(4))) float float4v;

#define MFMA16(a, b, c) __builtin_amdgcn_mfma_f32_16x16x32_bf16((a), (b), (c), 0, 0, 0)

static __device__ __forceinline__ unsigned short f2bf(float f) {
    unsigned u = __float_as_uint(f);
    u += 0x7FFFu + ((u >> 16) & 1u);   // RNE
    return (unsigned short)(u >> 16);
}
static __device__ __forceinline__ float bf2f(unsigned short h) {
    return __uint_as_float(((unsigned)h) << 16);
}

// async global->LDS, 16 B per lane. LDS dest is wave-uniform base + lane*16.
static __device__ __forceinline__ void gll16(const unsigned short* g, unsigned short* l) {
    __builtin_amdgcn_global_load_lds(
        (const __attribute__((address_space(1))) unsigned int*)g,
        (__attribute__((address_space(3))) unsigned int*)l, 16, 0, 0);
}

// ---------------------------------------------------------------------------
// Kernel 0: W (E,H) fp32 -> K-tiled split bf16 wtt[z][ks][128 h][32 k]
// ---------------------------------------------------------------------------
__global__ __launch_bounds__(256) void wtrans_kernel(
    const float* __restrict__ Wq, const float* __restrict__ Wk, const float* __restrict__ Wv,
    unsigned short* __restrict__ wtt_hi, unsigned short* __restrict__ wtt_lo)
{
    int t = blockIdx.x * 256 + threadIdx.x;   // 0..49151
    int kc8 = t & 3;
    int hh = (t >> 2) & 127;
    int ks = (t >> 9) & 31;
    int z = t >> 14;
    const float* W = (z == 0) ? Wq : ((z == 1) ? Wk : Wv);
    short8 h8, l8;
#pragma unroll
    for (int j = 0; j < 8; j++) {
        int e = ks * 32 + kc8 * 8 + j;
        float v = W[(size_t)e * Hn + hh];
        unsigned short hi = f2bf(v);
        h8[j] = (short)hi;
        l8[j] = (short)f2bf(v - bf2f(hi));
    }
    size_t d = (((size_t)z * 32 + ks) * 4096) + (size_t)hh * 32 + kc8 * 8;
    *(short8*)(wtt_hi + d) = h8;
    *(short8*)(wtt_lo + d) = l8;
}

// ---------------------------------------------------------------------------
// Kernel 0b: x fp32 -> K-tiled split bf16 xt[mt][ks][64 r][32 k].
// ---------------------------------------------------------------------------
__global__ __launch_bounds__(256) void xconv_kernel(
    const float* __restrict__ x,
    unsigned short* __restrict__ xt_hi, unsigned short* __restrict__ xt_lo)
{
    int g = blockIdx.x * 256 + threadIdx.x;   // 0..2097151
    int kc8 = g & 3;
    int rr = (g >> 2) & 63;
    int ks = (g >> 8) & 31;
    int mt = g >> 13;
    size_t src = ((size_t)mt * 64 + rr) * En + ks * 32 + kc8 * 8;
    float4v f0 = *(const float4v*)(x + src);
    float4v f1 = *(const float4v*)(x + src + 4);
    short8 h, l;
#pragma unroll
    for (int j = 0; j < 4; j++) {
        unsigned short h0 = f2bf(f0[j]);
        h[j] = (short)h0; l[j] = (short)f2bf(f0[j] - bf2f(h0));
        unsigned short h1 = f2bf(f1[j]);
        h[j + 4] = (short)h1; l[j + 4] = (short)f2bf(f1[j] - bf2f(h1));
    }
    size_t d = (size_t)g * 8;
    *(short8*)(xt_hi + d) = h;
    *(short8*)(xt_lo + d) = l;
}

// ---------------------------------------------------------------------------
// Kernel 1: projections, LDS double-buffered GEMM. v written s-chunk-tiled:
// vtt[b][sc][128 h][32 s] for out staging. (Validated R4/R5/R6.)
// ---------------------------------------------------------------------------
__global__ __launch_bounds__(256) void proj_kernel(
    const unsigned short* __restrict__ xt_hi, const unsigned short* __restrict__ xt_lo,
    const unsigned short* __restrict__ wtt_hi, const unsigned short* __restrict__ wtt_lo,
    unsigned short* __restrict__ q_hi, unsigned short* __restrict__ q_lo,
    unsigned short* __restrict__ k_hi, unsigned short* __restrict__ k_lo,
    unsigned short* __restrict__ vtt)
{
    __shared__ __align__(16) unsigned short lds[2][12288];  // 48 KB
    int z = blockIdx.y;
    int mt = blockIdx.x;                       // 0..255
    int tid = threadIdx.x;
    int wave = tid >> 6, lane = tid & 63;
    int c15 = lane & 15, kg = lane >> 4;
    int mrow = wave >> 1, ncol = wave & 1;     // 2x2 wave grid

    const unsigned short* Ah0 = xt_hi + (size_t)mt * 32 * 2048;
    const unsigned short* Al0 = xt_lo + (size_t)mt * 32 * 2048;
    const unsigned short* Bh0 = wtt_hi + (size_t)z * 32 * 4096;
    const unsigned short* Bl0 = wtt_lo + (size_t)z * 32 * 4096;

    float4v acc[2][4];
#pragma unroll
    for (int i = 0; i < 2; i++)
#pragma unroll
        for (int j = 0; j < 4; j++) acc[i][j] = (float4v)0.0f;

    auto stage = [&](int buf, int ks) {
        unsigned short* Lb = lds[buf];
        const unsigned short* Ah = Ah0 + ks * 2048;
        const unsigned short* Al = Al0 + ks * 2048;
        const unsigned short* Bh = Bh0 + ks * 4096;
        const unsigned short* Bl = Bl0 + ks * 4096;
        int lo8 = lane * 8;
        if (z < 2) {
#pragma unroll
            for (int i = 0; i < 6; i++) {
                int ch = wave * 6 + i;
                const unsigned short* g;
                unsigned short* l;
                if (ch < 4)       { g = Ah + ch * 512;        l = Lb + ch * 512; }
                else if (ch < 8)  { g = Al + (ch - 4) * 512;  l = Lb + 2048 + (ch - 4) * 512; }
                else if (ch < 16) { g = Bh + (ch - 8) * 512;  l = Lb + 4096 + (ch - 8) * 512; }
                else              { g = Bl + (ch - 16) * 512; l = Lb + 8192 + (ch - 16) * 512; }
                gll16(g + lo8, l + lo8);
            }
        } else {
#pragma unroll
            for (int i = 0; i < 3; i++) {
                int ch = wave * 3 + i;   // 0..11
                const unsigned short* g;
                unsigned short* l;
                if (ch < 4) { g = Ah + ch * 512;       l = Lb + ch * 512; }
                else        { g = Bh + (ch - 4) * 512; l = Lb + 4096 + (ch - 4) * 512; }
                gll16(g + lo8, l + lo8);
            }
        }
    };

    stage(0, 0);

    for (int ks = 0; ks < 32; ks++) {
        __syncthreads();
        if (ks + 1 < 32) stage((ks + 1) & 1, ks + 1);
        const unsigned short* Lb = lds[ks & 1];

        short8 ah[2], al[2], bh[4], bl[4];
#pragma unroll
        for (int mi = 0; mi < 2; mi++) {
            int row = mrow * 32 + mi * 16 + c15;
            ah[mi] = *(const short8*)(Lb + row * 32 + kg * 8);
        }
#pragma unroll
        for (int ni = 0; ni < 4; ni++) {
            int row = ncol * 64 + ni * 16 + c15;
            bh[ni] = *(const short8*)(Lb + 4096 + row * 32 + kg * 8);
        }
        if (z < 2) {
#pragma unroll
            for (int mi = 0; mi < 2; mi++) {
                int row = mrow * 32 + mi * 16 + c15;
                al[mi] = *(const short8*)(Lb + 2048 + row * 32 + kg * 8);
            }
#pragma unroll
            for (int ni = 0; ni < 4; ni++) {
                int row = ncol * 64 + ni * 16 + c15;
                bl[ni] = *(const short8*)(Lb + 8192 + row * 32 + kg * 8);
            }
#pragma unroll
            for (int mi = 0; mi < 2; mi++)
#pragma unroll
                for (int ni = 0; ni < 4; ni++) {
                    acc[mi][ni] = MFMA16(ah[mi], bh[ni], acc[mi][ni]);
                    acc[mi][ni] = MFMA16(ah[mi], bl[ni], acc[mi][ni]);
                    acc[mi][ni] = MFMA16(al[mi], bh[ni], acc[mi][ni]);
                }
        } else {
#pragma unroll
            for (int mi = 0; mi < 2; mi++)
#pragma unroll
                for (int ni = 0; ni < 4; ni++)
                    acc[mi][ni] = MFMA16(ah[mi], bh[ni], acc[mi][ni]);
        }
    }

    if (z < 2) {
        unsigned short* oh = (z == 0) ? q_hi : k_hi;
        unsigned short* ol = (z == 0) ? q_lo : k_lo;
#pragma unroll
        for (int mi = 0; mi < 2; mi++) {
#pragma unroll
            for (int ni = 0; ni < 4; ni++) {
                int h = ncol * 64 + ni * 16 + c15;
#pragma unroll
                for (int r = 0; r < 4; r++) {
                    int t = mt * 64 + mrow * 32 + mi * 16 + kg * 4 + r;
                    float v = acc[mi][ni][r];
                    unsigned short hh = f2bf(v);
                    unsigned short ll = f2bf(v - bf2f(hh));
                    size_t o = (size_t)t * Hn + h;
                    oh[o] = hh;
                    ol[o] = ll;
                }
            }
        }
    } else {
        int b = mt >> 5;
#pragma unroll
        for (int mi = 0; mi < 2; mi++) {
            int t0 = (mt & 31) * 64 + mrow * 32 + mi * 16 + kg * 4;
            int sc = t0 >> 5, so = t0 & 31;
#pragma unroll
            for (int ni = 0; ni < 4; ni++) {
                int h = ncol * 64 + ni * 16 + c15;
                short4v pk;
#pragma unroll
                for (int r = 0; r < 4; r++) pk[r] = (short)f2bf(acc[mi][ni][r]);
                *(short4v*)(vtt + (((size_t)b * 64 + sc) * 128 + h) * 32 + so) = pk;
            }
        }
    }
}

// ---------------------------------------------------------------------------
// Kernel 2: column softmax stats, LDS-staged, SINGLE-PASS (no splits/merge).
// Block = 4 waves; wave owns 16 s-rows (s-tile 64). All waves walk the same
// 32-t chunks c in [2*sj, 64), q staged via global_load_lds (dbuf). Each
// m_st/il_st cell written by exactly one thread. grid (32, B); sj=0 is the
// heaviest block and dispatches first (natural order).
// ---------------------------------------------------------------------------
__global__ __launch_bounds__(256) void stats_kernel(
    const unsigned short* __restrict__ q_hi, const unsigned short* __restrict__ q_lo,
    const unsigned short* __restrict__ k_hi, const unsigned short* __restrict__ k_lo,
    float* __restrict__ m_st, float* __restrict__ il_st)
{
    __shared__ __align__(16) unsigned short lds[2][8192];  // 32 KB
    int tid = threadIdx.x;
    int wave = tid >> 6, lane = tid & 63;
    int c15 = lane & 15, kg = lane >> 4;
    int b = blockIdx.y;
    int sj = blockIdx.x;                      // 0..31
    int s_base = sj * 64 + wave * 16;
    int c0 = 2 * sj, c1 = 64;

    // A fragments: wave's 16 k-rows (persist in regs)
    short8 a_h[4], a_l[4];
    {
        int s = s_base + c15;
        const unsigned short* kr = k_hi + ((size_t)(b * Tn + s)) * Hn + kg * 8;
        const unsigned short* krl = k_lo + ((size_t)(b * Tn + s)) * Hn + kg * 8;
#pragma unroll
        for (int st = 0; st < 4; st++) {
            a_h[st] = *(const short8*)(kr + st * 32);
            a_l[st] = *(const short8*)(krl + st * 32);
        }
    }
    float m[4], l[4];
#pragma unroll
    for (int r = 0; r < 4; r++) { m[r] = -3.0e38f; l[r] = 0.0f; }

    auto stage = [&](int buf, int c) {
        unsigned short* Lb = lds[buf];
        const unsigned short* Qh = q_hi + ((size_t)b * Tn + c * 32) * Hn;
        const unsigned short* Ql = q_lo + ((size_t)b * Tn + c * 32) * Hn;
        int lo8 = lane * 8;
#pragma unroll
        for (int i = 0; i < 4; i++) {
            int ch = wave * 4 + i;   // 0..15
            const unsigned short* g;
            unsigned short* ld;
            if (ch < 8) { g = Qh + ch * 512;       ld = Lb + ch * 512; }
            else        { g = Ql + (ch - 8) * 512; ld = Lb + 4096 + (ch - 8) * 512; }
            gll16(g + lo8, ld + lo8);
        }
    };

    stage(0, c0);
    for (int c = c0; c < c1; c++) {
        __syncthreads();
        if (c + 1 < c1) stage((c - c0 + 1) & 1, c + 1);
        const unsigned short* Lb = lds[(c - c0) & 1];
#pragma unroll
        for (int half = 0; half < 2; half++) {
            int t16 = c * 32 + half * 16;
            int tl = half * 16 + c15;
            float4v a1 = (float4v)0.0f, a2 = (float4v)0.0f, a3 = (float4v)0.0f;
#pragma unroll
            for (int st = 0; st < 4; st++) {
                short8 bh = *(const short8*)(Lb + tl * 128 + st * 32 + kg * 8);
                short8 bl = *(const short8*)(Lb + 4096 + tl * 128 + st * 32 + kg * 8);
                a1 = MFMA16(a_h[st], bh, a1);
                a2 = MFMA16(a_h[st], bl, a2);
                a3 = MFMA16(a_l[st], bh, a3);
            }
            int t = t16 + c15;
#pragma unroll
            for (int r = 0; r < 4; r++) {
                float attv = (a1[r] + a2[r] + a3[r]) * SQRTH;
                int s_row = s_base + kg * 4 + r;
                bool valid = (t >= s_row);
                float cand = valid ? attv : -3.0e38f;
                float mn = fmaxf(m[r], cand);
                l[r] = l[r] * __expf(m[r] - mn) + (valid ? __expf(attv - mn) : 0.0f);
                m[r] = mn;
            }
        }
    }
    // merge t-subsets across the 16 lanes sharing kg
#pragma unroll
    for (int mask = 1; mask < 16; mask <<= 1) {
#pragma unroll
        for (int r = 0; r < 4; r++) {
            float mo = __shfl_xor(m[r], mask);
            float lo2 = __shfl_xor(l[r], mask);
            float mn = fmaxf(m[r], mo);
            l[r] = l[r] * __expf(m[r] - mn) + lo2 * __expf(mo - mn);
            m[r] = mn;
        }
    }
    if (c15 == 0) {
#pragma unroll
        for (int r = 0; r < 4; r++) {
            int s = s_base + kg * 4 + r;
            m_st[b * Tn + s] = m[r];
            il_st[b * Tn + s] = 1.0f / l[r];
        }
    }
}

// ---------------------------------------------------------------------------
// Kernel 3: output, LDS-staged, SINGLE-PASS (no sg split, no partials, no
// atomics). Block = 4 waves; wave owns 16 t-rows (t-tile 64). All waves walk
// chunks c in [0, 2*tj+2): k_hi/k_lo + vtt staged via global_load_lds (dbuf).
// Direct coalesced stores to out — each cell written exactly once.
// grid (32, B), heavy (large tj) dispatched first.
// ---------------------------------------------------------------------------
__global__ __launch_bounds__(256) void out_kernel(
    const unsigned short* __restrict__ q_hi, const unsigned short* __restrict__ q_lo,
    const unsigned short* __restrict__ k_hi, const unsigned short* __restrict__ k_lo,
    const unsigned short* __restrict__ vtt,
    const float* __restrict__ m_st, const float* __restrict__ il_st,
    float* __restrict__ out)
{
    __shared__ __align__(16) unsigned short lds[2][12288];   // 48 KB
    __shared__ __align__(16) unsigned short pbuf[4][16][40]; // 5 KB
    int tid = threadIdx.x;
    int wave = tid >> 6, lane = tid & 63;
    int c15 = lane & 15, kg = lane >> 4;
    int b = blockIdx.y;
    int tj = 31 - (int)blockIdx.x;            // heavy (large tj) first
    int t_base = tj * 64 + wave * 16;
    int c1 = 2 * tj + 2;

    // A fragments: wave's 16 q-rows (persist)
    short8 qa_h[4], qa_l[4];
    {
        int t = t_base + c15;
        const unsigned short* qr = q_hi + ((size_t)(b * Tn + t)) * Hn + kg * 8;
        const unsigned short* qrl = q_lo + ((size_t)(b * Tn + t)) * Hn + kg * 8;
#pragma unroll
        for (int st = 0; st < 4; st++) {
            qa_h[st] = *(const short8*)(qr + st * 32);
            qa_l[st] = *(const short8*)(qrl + st * 32);
        }
    }
    float4v oacc[8];
#pragma unroll
    for (int i = 0; i < 8; i++) oacc[i] = (float4v)0.0f;

    auto stage = [&](int buf, int c) {
        unsigned short* Lb = lds[buf];
        const unsigned short* Kh = k_hi + ((size_t)b * Tn + c * 32) * Hn;
        const unsigned short* Kl = k_lo + ((size_t)b * Tn + c * 32) * Hn;
        const unsigned short* Vv = vtt + ((size_t)b * 64 + c) * (128 * 32);
        int lo8 = lane * 8;
#pragma unroll
        for (int i = 0; i < 6; i++) {
            int ch = wave * 6 + i;   // 0..23
            const unsigned short* g;
            unsigned short* ld;
            if (ch < 8)       { g = Kh + ch * 512;        ld = Lb + ch * 512; }
            else if (ch < 16) { g = Kl + (ch - 8) * 512;  ld = Lb + 4096 + (ch - 8) * 512; }
            else              { g = Vv + (ch - 16) * 512; ld = Lb + 8192 + (ch - 16) * 512; }
            gll16(g + lo8, ld + lo8);
        }
    };

    stage(0, 0);
    for (int c = 0; c < c1; c++) {
        __syncthreads();
        if (c + 1 < c1) stage((c + 1) & 1, c + 1);
        const unsigned short* Lb = lds[c & 1];
#pragma unroll
        for (int half = 0; half < 2; half++) {
            int s16 = c * 32 + half * 16;
            int sl = half * 16 + c15;
            float4v a1 = (float4v)0.0f, a2 = (float4v)0.0f, a3 = (float4v)0.0f;
#pragma unroll
            for (int st = 0; st < 4; st++) {
                short8 bh = *(const short8*)(Lb + sl * 128 + st * 32 + kg * 8);
                short8 bl = *(const short8*)(Lb + 4096 + sl * 128 + st * 32 + kg * 8);
                a1 = MFMA16(qa_h[st], bh, a1);
                a2 = MFMA16(qa_h[st], bl, a2);
                a3 = MFMA16(qa_l[st], bh, a3);
            }
            float msv = m_st[b * Tn + s16 + c15];
            float ilv = il_st[b * Tn + s16 + c15];
#pragma unroll
            for (int r = 0; r < 4; r++) {
                int t = t_base + kg * 4 + r;
                float attv = (a1[r] + a2[r] + a3[r]) * SQRTH;
                float p = (t >= s16 + c15) ? __expf(attv - msv) * ilv : 0.0f;
                pbuf[wave][kg * 4 + r][c15 + half * 16] = f2bf(p);
            }
        }
        // C-layout -> A-layout via LDS (wave-internal, DS pipe in-order)
        short8 pa = *(const short8*)&pbuf[wave][c15][kg * 8];
#pragma unroll
        for (int nt = 0; nt < 8; nt++) {
            short8 vb = *(const short8*)(Lb + 8192 + (nt * 16 + c15) * 32 + kg * 8);
            oacc[nt] = MFMA16(pa, vb, oacc[nt]);
        }
    }
    // direct stores: this block exclusively owns rows [t_base, t_base+16)
#pragma unroll
    for (int nt = 0; nt < 8; nt++) {
        int h = nt * 16 + c15;
#pragma unroll
        for (int r = 0; r < 4; r++) {
            int t = t_base + kg * 4 + r;
            out[((size_t)b * Tn + t) * Hn + h] = oacc[nt][r];
        }
    }
}

// ---------------------------------------------------------------------------
extern "C" void kernel_launch(void* const* d_in, const int* in_sizes, int n_in,
                              void* d_out, int out_size, void* d_ws, size_t ws_size,
                              hipStream_t stream)
{
    (void)in_sizes; (void)n_in; (void)out_size; (void)ws_size;
    const float* x  = (const float*)d_in[0];
    const float* Wk = (const float*)d_in[1];
    const float* Wq = (const float*)d_in[2];
    const float* Wv = (const float*)d_in[3];
    float* out = (float*)d_out;

    const size_t NQ = (size_t)Bn * Tn * Hn;        // 2,097,152
    const size_t NX = (size_t)Bn * Tn * En;        // 16,777,216
    unsigned short* q_hi = (unsigned short*)d_ws;
    unsigned short* q_lo = q_hi + NQ;
    unsigned short* k_hi = q_lo + NQ;
    unsigned short* k_lo = k_hi + NQ;
    unsigned short* vtt  = k_lo + NQ;
    unsigned short* xt_hi = vtt + NQ;
    unsigned short* xt_lo = xt_hi + NX;
    unsigned short* wtt_hi = xt_lo + NX;
    unsigned short* wtt_lo = wtt_hi + (size_t)3 * Hn * En;
    float* m_st  = (float*)(wtt_lo + (size_t)3 * Hn * En);
    float* il_st = m_st + (size_t)Bn * Tn;
    // total ws use: ~89.4 MB — identical extent to the validated R4 layout

    wtrans_kernel<<<dim3(192), 256, 0, stream>>>(Wq, Wk, Wv, wtt_hi, wtt_lo);
    xconv_kernel<<<dim3(8192), 256, 0, stream>>>(x, xt_hi, xt_lo);
    proj_kernel<<<dim3(256, 3), 256, 0, stream>>>(xt_hi, xt_lo, wtt_hi, wtt_lo,
                                                  q_hi, q_lo, k_hi, k_lo, vtt);
    stats_kernel<<<dim3(32, Bn), 256, 0, stream>>>(q_hi, q_lo, k_hi, k_lo, m_st, il_st);
    out_kernel<<<dim3(32, Bn), 256, 0, stream>>>(q_hi, q_lo, k_hi, k_lo, vtt,
                                                 m_st, il_st, out);
}

// Round 8
// 314.368 us; speedup vs baseline: 1.7386x; 1.1580x over previous
//
#include <hip/hip_runtime.h>
#include <math.h>

#define Bn 8
#define Tn 2048
#define En 1024
#define Hn 128
#define SQRTH 11.313708498984761f

typedef __attribute__((ext_vector_type(8))) short short8;
typedef __attribute__((ext_vector_type(4))) short short4v;
typedef __attribute__((ext_vector_type(4))) float float4v;

#define MFMA16(a, b, c) __builtin_amdgcn_mfma_f32_16x16x32_bf16((a), (b), (c), 0, 0, 0)

static __device__ __forceinline__ unsigned short f2bf(float f) {
    unsigned u = __float_as_uint(f);
    u += 0x7FFFu + ((u >> 16) & 1u);   // RNE
    return (unsigned short)(u >> 16);
}
static __device__ __forceinline__ float bf2f(unsigned short h) {
    return __uint_as_float(((unsigned)h) << 16);
}

// async global->LDS, 16 B per lane. LDS dest is wave-uniform base + lane*16.
static __device__ __forceinline__ void gll16(const unsigned short* g, unsigned short* l) {
    __builtin_amdgcn_global_load_lds(
        (const __attribute__((address_space(1))) unsigned int*)g,
        (__attribute__((address_space(3))) unsigned int*)l, 16, 0, 0);
}

// ---------------------------------------------------------------------------
// SWIZZLE (bank-conflict fix, R8): q/k rows are 128 shorts = 16 blocks of
// 16 B; block j of row t is stored at j ^ (t & 15). Staged-LDS b128 reads
// then hit bank-group ((4*st+kg) ^ c15) % 8 -> 2 lanes/bank = free (m136).
// vtt rows are 32 shorts = 4 blocks; block j of row h stored at
// j ^ ((h>>1) & 3) -> 2-way = free. Swizzle is baked into the GLOBAL layout
// (global_load_lds forces LDS order == global order); all readers adjust.
// ---------------------------------------------------------------------------

// ---------------------------------------------------------------------------
// Kernel 0: W (E,H) fp32 -> K-tiled split bf16 wtt[z][ks][128 h][32 k]
// ---------------------------------------------------------------------------
__global__ __launch_bounds__(256) void wtrans_kernel(
    const float* __restrict__ Wq, const float* __restrict__ Wk, const float* __restrict__ Wv,
    unsigned short* __restrict__ wtt_hi, unsigned short* __restrict__ wtt_lo)
{
    int t = blockIdx.x * 256 + threadIdx.x;   // 0..49151
    int kc8 = t & 3;
    int hh = (t >> 2) & 127;
    int ks = (t >> 9) & 31;
    int z = t >> 14;
    const float* W = (z == 0) ? Wq : ((z == 1) ? Wk : Wv);
    short8 h8, l8;
#pragma unroll
    for (int j = 0; j < 8; j++) {
        int e = ks * 32 + kc8 * 8 + j;
        float v = W[(size_t)e * Hn + hh];
        unsigned short hi = f2bf(v);
        h8[j] = (short)hi;
        l8[j] = (short)f2bf(v - bf2f(hi));
    }
    size_t d = (((size_t)z * 32 + ks) * 4096) + (size_t)hh * 32 + kc8 * 8;
    *(short8*)(wtt_hi + d) = h8;
    *(short8*)(wtt_lo + d) = l8;
}

// ---------------------------------------------------------------------------
// Kernel 0b: x fp32 -> K-tiled split bf16 xt[mt][ks][64 r][32 k].
// ---------------------------------------------------------------------------
__global__ __launch_bounds__(256) void xconv_kernel(
    const float* __restrict__ x,
    unsigned short* __restrict__ xt_hi, unsigned short* __restrict__ xt_lo)
{
    int g = blockIdx.x * 256 + threadIdx.x;   // 0..2097151
    int kc8 = g & 3;
    int rr = (g >> 2) & 63;
    int ks = (g >> 8) & 31;
    int mt = g >> 13;
    size_t src = ((size_t)mt * 64 + rr) * En + ks * 32 + kc8 * 8;
    float4v f0 = *(const float4v*)(x + src);
    float4v f1 = *(const float4v*)(x + src + 4);
    short8 h, l;
#pragma unroll
    for (int j = 0; j < 4; j++) {
        unsigned short h0 = f2bf(f0[j]);
        h[j] = (short)h0; l[j] = (short)f2bf(f0[j] - bf2f(h0));
        unsigned short h1 = f2bf(f1[j]);
        h[j + 4] = (short)h1; l[j + 4] = (short)f2bf(f1[j] - bf2f(h1));
    }
    size_t d = (size_t)g * 8;
    *(short8*)(xt_hi + d) = h;
    *(short8*)(xt_lo + d) = l;
}

// ---------------------------------------------------------------------------
// Kernel 1: projections, LDS double-buffered GEMM. q/k written with the
// 16-B-block row swizzle; v written s-chunk-tiled vtt[b][sc][128 h][32 s]
// with the 4-block swizzle. (Internal LDS rows are 64 B -> already 2-way.)
// ---------------------------------------------------------------------------
__global__ __launch_bounds__(256) void proj_kernel(
    const unsigned short* __restrict__ xt_hi, const unsigned short* __restrict__ xt_lo,
    const unsigned short* __restrict__ wtt_hi, const unsigned short* __restrict__ wtt_lo,
    unsigned short* __restrict__ q_hi, unsigned short* __restrict__ q_lo,
    unsigned short* __restrict__ k_hi, unsigned short* __restrict__ k_lo,
    unsigned short* __restrict__ vtt)
{
    __shared__ __align__(16) unsigned short lds[2][12288];  // 48 KB
    int z = blockIdx.y;
    int mt = blockIdx.x;                       // 0..255
    int tid = threadIdx.x;
    int wave = tid >> 6, lane = tid & 63;
    int c15 = lane & 15, kg = lane >> 4;
    int mrow = wave >> 1, ncol = wave & 1;     // 2x2 wave grid

    const unsigned short* Ah0 = xt_hi + (size_t)mt * 32 * 2048;
    const unsigned short* Al0 = xt_lo + (size_t)mt * 32 * 2048;
    const unsigned short* Bh0 = wtt_hi + (size_t)z * 32 * 4096;
    const unsigned short* Bl0 = wtt_lo + (size_t)z * 32 * 4096;

    float4v acc[2][4];
#pragma unroll
    for (int i = 0; i < 2; i++)
#pragma unroll
        for (int j = 0; j < 4; j++) acc[i][j] = (float4v)0.0f;

    auto stage = [&](int buf, int ks) {
        unsigned short* Lb = lds[buf];
        const unsigned short* Ah = Ah0 + ks * 2048;
        const unsigned short* Al = Al0 + ks * 2048;
        const unsigned short* Bh = Bh0 + ks * 4096;
        const unsigned short* Bl = Bl0 + ks * 4096;
        int lo8 = lane * 8;
        if (z < 2) {
#pragma unroll
            for (int i = 0; i < 6; i++) {
                int ch = wave * 6 + i;
                const unsigned short* g;
                unsigned short* l;
                if (ch < 4)       { g = Ah + ch * 512;        l = Lb + ch * 512; }
                else if (ch < 8)  { g = Al + (ch - 4) * 512;  l = Lb + 2048 + (ch - 4) * 512; }
                else if (ch < 16) { g = Bh + (ch - 8) * 512;  l = Lb + 4096 + (ch - 8) * 512; }
                else              { g = Bl + (ch - 16) * 512; l = Lb + 8192 + (ch - 16) * 512; }
                gll16(g + lo8, l + lo8);
            }
        } else {
#pragma unroll
            for (int i = 0; i < 3; i++) {
                int ch = wave * 3 + i;   // 0..11
                const unsigned short* g;
                unsigned short* l;
                if (ch < 4) { g = Ah + ch * 512;       l = Lb + ch * 512; }
                else        { g = Bh + (ch - 4) * 512; l = Lb + 4096 + (ch - 4) * 512; }
                gll16(g + lo8, l + lo8);
            }
        }
    };

    stage(0, 0);

    for (int ks = 0; ks < 32; ks++) {
        __syncthreads();
        if (ks + 1 < 32) stage((ks + 1) & 1, ks + 1);
        const unsigned short* Lb = lds[ks & 1];

        short8 ah[2], al[2], bh[4], bl[4];
#pragma unroll
        for (int mi = 0; mi < 2; mi++) {
            int row = mrow * 32 + mi * 16 + c15;
            ah[mi] = *(const short8*)(Lb + row * 32 + kg * 8);
        }
#pragma unroll
        for (int ni = 0; ni < 4; ni++) {
            int row = ncol * 64 + ni * 16 + c15;
            bh[ni] = *(const short8*)(Lb + 4096 + row * 32 + kg * 8);
        }
        if (z < 2) {
#pragma unroll
            for (int mi = 0; mi < 2; mi++) {
                int row = mrow * 32 + mi * 16 + c15;
                al[mi] = *(const short8*)(Lb + 2048 + row * 32 + kg * 8);
            }
#pragma unroll
            for (int ni = 0; ni < 4; ni++) {
                int row = ncol * 64 + ni * 16 + c15;
                bl[ni] = *(const short8*)(Lb + 8192 + row * 32 + kg * 8);
            }
#pragma unroll
            for (int mi = 0; mi < 2; mi++)
#pragma unroll
                for (int ni = 0; ni < 4; ni++) {
                    acc[mi][ni] = MFMA16(ah[mi], bh[ni], acc[mi][ni]);
                    acc[mi][ni] = MFMA16(ah[mi], bl[ni], acc[mi][ni]);
                    acc[mi][ni] = MFMA16(al[mi], bh[ni], acc[mi][ni]);
                }
        } else {
#pragma unroll
            for (int mi = 0; mi < 2; mi++)
#pragma unroll
                for (int ni = 0; ni < 4; ni++)
                    acc[mi][ni] = MFMA16(ah[mi], bh[ni], acc[mi][ni]);
        }
    }

    if (z < 2) {
        unsigned short* oh = (z == 0) ? q_hi : k_hi;
        unsigned short* ol = (z == 0) ? q_lo : k_lo;
#pragma unroll
        for (int mi = 0; mi < 2; mi++) {
#pragma unroll
            for (int ni = 0; ni < 4; ni++) {
                int h = ncol * 64 + ni * 16 + c15;
#pragma unroll
                for (int r = 0; r < 4; r++) {
                    int t = mt * 64 + mrow * 32 + mi * 16 + kg * 4 + r;
                    float v = acc[mi][ni][r];
                    unsigned short hh = f2bf(v);
                    unsigned short ll = f2bf(v - bf2f(hh));
                    // swizzled: block (h>>3) of row t -> (h>>3) ^ (t&15)
                    size_t o = (size_t)t * Hn + (((h >> 3) ^ (t & 15)) << 3) + (h & 7);
                    oh[o] = hh;
                    ol[o] = ll;
                }
            }
        }
    } else {
        int b = mt >> 5;
#pragma unroll
        for (int mi = 0; mi < 2; mi++) {
            int t0 = (mt & 31) * 64 + mrow * 32 + mi * 16 + kg * 4;
            int sc = t0 >> 5, so = t0 & 31;
#pragma unroll
            for (int ni = 0; ni < 4; ni++) {
                int h = ncol * 64 + ni * 16 + c15;
                short4v pk;
#pragma unroll
                for (int r = 0; r < 4; r++) pk[r] = (short)f2bf(acc[mi][ni][r]);
                // swizzled: block (so>>3) of row h -> (so>>3) ^ ((h>>1)&3)
                int so2 = ((((so >> 3) ^ ((h >> 1) & 3))) << 3) | (so & 7);
                *(short4v*)(vtt + (((size_t)b * 64 + sc) * 128 + h) * 32 + so2) = pk;
            }
        }
    }
}

// ---------------------------------------------------------------------------
// Kernel 2: column softmax stats, LDS-staged, single-pass. Swizzle-aware
// reads (global A-fragments and staged-LDS B-fragments). grid (32, B).
// ---------------------------------------------------------------------------
__global__ __launch_bounds__(256) void stats_kernel(
    const unsigned short* __restrict__ q_hi, const unsigned short* __restrict__ q_lo,
    const unsigned short* __restrict__ k_hi, const unsigned short* __restrict__ k_lo,
    float* __restrict__ m_st, float* __restrict__ il_st)
{
    __shared__ __align__(16) unsigned short lds[2][8192];  // 32 KB
    int tid = threadIdx.x;
    int wave = tid >> 6, lane = tid & 63;
    int c15 = lane & 15, kg = lane >> 4;
    int b = blockIdx.y;
    int sj = blockIdx.x;                      // 0..31
    int s_base = sj * 64 + wave * 16;
    int c0 = 2 * sj, c1 = 64;

    // A fragments: wave's 16 k-rows; s&15 == c15 (s_base is x16-aligned)
    short8 a_h[4], a_l[4];
    {
        int s = s_base + c15;
        const unsigned short* kr = k_hi + ((size_t)(b * Tn + s)) * Hn;
        const unsigned short* krl = k_lo + ((size_t)(b * Tn + s)) * Hn;
#pragma unroll
        for (int st = 0; st < 4; st++) {
            int off = ((st * 4 + kg) ^ c15) * 8;
            a_h[st] = *(const short8*)(kr + off);
            a_l[st] = *(const short8*)(krl + off);
        }
    }
    float m[4], l[4];
#pragma unroll
    for (int r = 0; r < 4; r++) { m[r] = -3.0e38f; l[r] = 0.0f; }

    auto stage = [&](int buf, int c) {
        unsigned short* Lb = lds[buf];
        const unsigned short* Qh = q_hi + ((size_t)b * Tn + c * 32) * Hn;
        const unsigned short* Ql = q_lo + ((size_t)b * Tn + c * 32) * Hn;
        int lo8 = lane * 8;
#pragma unroll
        for (int i = 0; i < 4; i++) {
            int ch = wave * 4 + i;   // 0..15
            const unsigned short* g;
            unsigned short* ld;
            if (ch < 8) { g = Qh + ch * 512;       ld = Lb + ch * 512; }
            else        { g = Ql + (ch - 8) * 512; ld = Lb + 4096 + (ch - 8) * 512; }
            gll16(g + lo8, ld + lo8);
        }
    };

    stage(0, c0);
    for (int c = c0; c < c1; c++) {
        __syncthreads();
        if (c + 1 < c1) stage((c - c0 + 1) & 1, c + 1);
        const unsigned short* Lb = lds[(c - c0) & 1];
#pragma unroll
        for (int half = 0; half < 2; half++) {
            int t16 = c * 32 + half * 16;
            int tl = half * 16 + c15;
            float4v a1 = (float4v)0.0f, a2 = (float4v)0.0f, a3 = (float4v)0.0f;
#pragma unroll
            for (int st = 0; st < 4; st++) {
                // swizzled block ((st*4+kg) ^ (t&15)); t&15 == c15
                int off = tl * 128 + ((st * 4 + kg) ^ c15) * 8;
                short8 bh = *(const short8*)(Lb + off);
                short8 bl = *(const short8*)(Lb + 4096 + off);
                a1 = MFMA16(a_h[st], bh, a1);
                a2 = MFMA16(a_h[st], bl, a2);
                a3 = MFMA16(a_l[st], bh, a3);
            }
            int t = t16 + c15;
#pragma unroll
            for (int r = 0; r < 4; r++) {
                float attv = (a1[r] + a2[r] + a3[r]) * SQRTH;
                int s_row = s_base + kg * 4 + r;
                bool valid = (t >= s_row);
                float cand = valid ? attv : -3.0e38f;
                float mn = fmaxf(m[r], cand);
                l[r] = l[r] * __expf(m[r] - mn) + (valid ? __expf(attv - mn) : 0.0f);
                m[r] = mn;
            }
        }
    }
    // merge t-subsets across the 16 lanes sharing kg
#pragma unroll
    for (int mask = 1; mask < 16; mask <<= 1) {
#pragma unroll
        for (int r = 0; r < 4; r++) {
            float mo = __shfl_xor(m[r], mask);
            float lo2 = __shfl_xor(l[r], mask);
            float mn = fmaxf(m[r], mo);
            l[r] = l[r] * __expf(m[r] - mn) + lo2 * __expf(mo - mn);
            m[r] = mn;
        }
    }
    if (c15 == 0) {
#pragma unroll
        for (int r = 0; r < 4; r++) {
            int s = s_base + kg * 4 + r;
            m_st[b * Tn + s] = m[r];
            il_st[b * Tn + s] = 1.0f / l[r];
        }
    }
}

// ---------------------------------------------------------------------------
// Kernel 3: output, LDS-staged, single-pass, swizzle-aware.
// grid (32, B), heavy (large tj) dispatched first.
// ---------------------------------------------------------------------------
__global__ __launch_bounds__(256) void out_kernel(
    const unsigned short* __restrict__ q_hi, const unsigned short* __restrict__ q_lo,
    const unsigned short* __restrict__ k_hi, const unsigned short* __restrict__ k_lo,
    const unsigned short* __restrict__ vtt,
    const float* __restrict__ m_st, const float* __restrict__ il_st,
    float* __restrict__ out)
{
    __shared__ __align__(16) unsigned short lds[2][12288];   // 48 KB
    __shared__ __align__(16) unsigned short pbuf[4][16][40]; // 5 KB
    int tid = threadIdx.x;
    int wave = tid >> 6, lane = tid & 63;
    int c15 = lane & 15, kg = lane >> 4;
    int b = blockIdx.y;
    int tj = 31 - (int)blockIdx.x;            // heavy (large tj) first
    int t_base = tj * 64 + wave * 16;
    int c1 = 2 * tj + 2;

    // A fragments: wave's 16 q-rows; t&15 == c15
    short8 qa_h[4], qa_l[4];
    {
        int t = t_base + c15;
        const unsigned short* qr = q_hi + ((size_t)(b * Tn + t)) * Hn;
        const unsigned short* qrl = q_lo + ((size_t)(b * Tn + t)) * Hn;
#pragma unroll
        for (int st = 0; st < 4; st++) {
            int off = ((st * 4 + kg) ^ c15) * 8;
            qa_h[st] = *(const short8*)(qr + off);
            qa_l[st] = *(const short8*)(qrl + off);
        }
    }
    float4v oacc[8];
#pragma unroll
    for (int i = 0; i < 8; i++) oacc[i] = (float4v)0.0f;

    auto stage = [&](int buf, int c) {
        unsigned short* Lb = lds[buf];
        const unsigned short* Kh = k_hi + ((size_t)b * Tn + c * 32) * Hn;
        const unsigned short* Kl = k_lo + ((size_t)b * Tn + c * 32) * Hn;
        const unsigned short* Vv = vtt + ((size_t)b * 64 + c) * (128 * 32);
        int lo8 = lane * 8;
#pragma unroll
        for (int i = 0; i < 6; i++) {
            int ch = wave * 6 + i;   // 0..23
            const unsigned short* g;
            unsigned short* ld;
            if (ch < 8)       { g = Kh + ch * 512;        ld = Lb + ch * 512; }
            else if (ch < 16) { g = Kl + (ch - 8) * 512;  ld = Lb + 4096 + (ch - 8) * 512; }
            else              { g = Vv + (ch - 16) * 512; ld = Lb + 8192 + (ch - 16) * 512; }
            gll16(g + lo8, ld + lo8);
        }
    };

    stage(0, 0);
    for (int c = 0; c < c1; c++) {
        __syncthreads();
        if (c + 1 < c1) stage((c + 1) & 1, c + 1);
        const unsigned short* Lb = lds[c & 1];
#pragma unroll
        for (int half = 0; half < 2; half++) {
            int s16 = c * 32 + half * 16;
            int sl = half * 16 + c15;
            float4v a1 = (float4v)0.0f, a2 = (float4v)0.0f, a3 = (float4v)0.0f;
#pragma unroll
            for (int st = 0; st < 4; st++) {
                // swizzled block ((st*4+kg) ^ (s&15)); s&15 == c15
                int off = sl * 128 + ((st * 4 + kg) ^ c15) * 8;
                short8 bh = *(const short8*)(Lb + off);
                short8 bl = *(const short8*)(Lb + 4096 + off);
                a1 = MFMA16(qa_h[st], bh, a1);
                a2 = MFMA16(qa_h[st], bl, a2);
                a3 = MFMA16(qa_l[st], bh, a3);
            }
            float msv = m_st[b * Tn + s16 + c15];
            float ilv = il_st[b * Tn + s16 + c15];
#pragma unroll
            for (int r = 0; r < 4; r++) {
                int t = t_base + kg * 4 + r;
                float attv = (a1[r] + a2[r] + a3[r]) * SQRTH;
                float p = (t >= s16 + c15) ? __expf(attv - msv) * ilv : 0.0f;
                pbuf[wave][kg * 4 + r][c15 + half * 16] = f2bf(p);
            }
        }
        // C-layout -> A-layout via LDS (wave-internal, DS pipe in-order)
        short8 pa = *(const short8*)&pbuf[wave][c15][kg * 8];
#pragma unroll
        for (int nt = 0; nt < 8; nt++) {
            // vtt row h = nt*16+c15; swizzled block kg ^ ((h>>1)&3),
            // (h>>1)&3 == (c15>>1)&3 since nt*16 is a multiple of 8 in h>>1
            int voff = (nt * 16 + c15) * 32 + ((kg ^ ((c15 >> 1) & 3)) * 8);
            short8 vb = *(const short8*)(Lb + 8192 + voff);
            oacc[nt] = MFMA16(pa, vb, oacc[nt]);
        }
    }
    // direct stores: this block exclusively owns rows [t_base, t_base+16)
#pragma unroll
    for (int nt = 0; nt < 8; nt++) {
        int h = nt * 16 + c15;
#pragma unroll
        for (int r = 0; r < 4; r++) {
            int t = t_base + kg * 4 + r;
            out[((size_t)b * Tn + t) * Hn + h] = oacc[nt][r];
        }
    }
}

// ---------------------------------------------------------------------------
extern "C" void kernel_launch(void* const* d_in, const int* in_sizes, int n_in,
                              void* d_out, int out_size, void* d_ws, size_t ws_size,
                              hipStream_t stream)
{
    (void)in_sizes; (void)n_in; (void)out_size; (void)ws_size;
    const float* x  = (const float*)d_in[0];
    const float* Wk = (const float*)d_in[1];
    const float* Wq = (const float*)d_in[2];
    const float* Wv = (const float*)d_in[3];
    float* out = (float*)d_out;

    const size_t NQ = (size_t)Bn * Tn * Hn;        // 2,097,152
    const size_t NX = (size_t)Bn * Tn * En;        // 16,777,216
    unsigned short* q_hi = (unsigned short*)d_ws;
    unsigned short* q_lo = q_hi + NQ;
    unsigned short* k_hi = q_lo + NQ;
    unsigned short* k_lo = k_hi + NQ;
    unsigned short* vtt  = k_lo + NQ;
    unsigned short* xt_hi = vtt + NQ;
    unsigned short* xt_lo = xt_hi + NX;
    unsigned short* wtt_hi = xt_lo + NX;
    unsigned short* wtt_lo = wtt_hi + (size_t)3 * Hn * En;
    float* m_st  = (float*)(wtt_lo + (size_t)3 * Hn * En);
    float* il_st = m_st + (size_t)Bn * Tn;
    // total ws use: ~89.4 MB — identical extent to the validated R7 layout

    wtrans_kernel<<<dim3(192), 256, 0, stream>>>(Wq, Wk, Wv, wtt_hi, wtt_lo);
    xconv_kernel<<<dim3(8192), 256, 0, stream>>>(x, xt_hi, xt_lo);
    proj_kernel<<<dim3(256, 3), 256, 0, stream>>>(xt_hi, xt_lo, wtt_hi, wtt_lo,
                                                  q_hi, q_lo, k_hi, k_lo, vtt);
    stats_kernel<<<dim3(32, Bn), 256, 0, stream>>>(q_hi, q_lo, k_hi, k_lo, m_st, il_st);
    out_kernel<<<dim3(32, Bn), 256, 0, stream>>>(q_hi, q_lo, k_hi, k_lo, vtt,
                                                 m_st, il_st, out);
}